// Round 3
// baseline (567.463 us; speedup 1.0000x reference)
//
#include <hip/hip_runtime.h>
#include <math.h>

#define COMMITMENT_COST 0.25f
#define DECAY 0.99f
#define EPSILON 1e-05f
#define KCODES 1024
#define DIM 256
#define NTOK 32768

// out-buffer float offsets (concatenated return tuple)
#define O_QUANT 0
#define O_LOSS  8388608
#define O_IDX   8388609
#define O_CS    8421377   // counts accumulator -> new_cluster_size
#define O_EMAW  8422401   // dw accumulator -> new_ema_w
#define O_EMB   8684545   // esq scratch (first 1024) -> new_embedding

// ---------------- Kernel A0: zsq[n] = sum_d z[n][d]^2 ----------------
// scratch lives at head of quantized slot; gather overwrites it later
__global__ void zsq_kernel(const float* __restrict__ z, float* __restrict__ zsq) {
    int wave = threadIdx.x >> 6;
    int lane = threadIdx.x & 63;
    int token = blockIdx.x * 4 + wave;         // 8192 blocks * 4 tokens
    const float4* zp = (const float4*)(z + (size_t)token * DIM);
    float4 v = zp[lane];
    float s = v.x * v.x + v.y * v.y + v.z * v.z + v.w * v.w;
    #pragma unroll
    for (int off = 32; off > 0; off >>= 1) s += __shfl_down(s, off);
    if (lane == 0) zsq[token] = s;
}

// ---------------- Kernel A1: esq[k] = sum_d E[k][d]^2 ----------------
__global__ void esq_kernel(const float* __restrict__ E, float* __restrict__ esq) {
    int wave = threadIdx.x >> 6;
    int lane = threadIdx.x & 63;
    int k = blockIdx.x * 4 + wave;            // 256 blocks * 4 rows
    const float4* ep = (const float4*)(E + (size_t)k * DIM);
    float4 v = ep[lane];
    float s = v.x * v.x + v.y * v.y + v.z * v.z + v.w * v.w;
    #pragma unroll
    for (int off = 32; off > 0; off >>= 1) s += __shfl_down(s, off);
    if (lane == 0) esq[k] = s;
}

// ---------------- Kernel B: fused distances + argmin ----------------
// Replicates reference fp32 semantics: d = fl(fl(||z||^2 + ||e||^2) - 2*z.e)
// at magnitude ~256, argmin with FIRST-INDEX tie-break on equal fp32 values.
// block: 256 thr; tile: 64 tokens x 128 codes per k-step; thread: 4 tok x 8 k
__global__ __launch_bounds__(256) void dist_argmin_kernel(
        const float* __restrict__ z, const float* __restrict__ E,
        const float* __restrict__ esq, const float* __restrict__ zsq,
        float* __restrict__ idx_out) {
    __shared__ float zs[64 * 68];    // 64 tokens x 64 d (pad 68)
    __shared__ float es[128 * 68];   // 128 codes x 64 d (pad 68)
    __shared__ float sq[128];

    const int tid = threadIdx.x;
    const int r = tid >> 4;          // 0..15 -> tokens r*4 .. r*4+3
    const int c = tid & 15;          // codes c + 16*j, j=0..7
    const int tok0 = blockIdx.x * 64;

    float An[4];
    #pragma unroll
    for (int i = 0; i < 4; ++i) An[i] = zsq[tok0 + r * 4 + i];

    float best[4];
    int bidx[4];
    #pragma unroll
    for (int i = 0; i < 4; ++i) { best[i] = 3.4e38f; bidx[i] = 0x7fffffff; }

    const int zt = tid >> 2, zsb = tid & 3;       // z staging: token zt, 4 f4
    const int ek = tid >> 1, esb = tid & 1;       // E staging: code ek, 8 f4

    for (int kt = 0; kt < 8; ++kt) {
        const int k0 = kt * 128;
        __syncthreads();                           // protect sq from prev epilogue
        if (tid < 128) sq[tid] = esq[k0 + tid];

        float acc[4][8];
        #pragma unroll
        for (int i = 0; i < 4; ++i)
            #pragma unroll
            for (int j = 0; j < 8; ++j) acc[i][j] = 0.0f;

        for (int dc = 0; dc < 4; ++dc) {
            const int d0 = dc * 64;
            __syncthreads();                       // prev compute done
            {   // stage z tile: 64 tok x 64 d
                const float* zp = z + (size_t)(tok0 + zt) * DIM + d0;
                float* zd = zs + zt * 68;
                #pragma unroll
                for (int q = 0; q < 4; ++q) {
                    int col = zsb * 4 + q * 16;
                    *(float4*)(zd + col) = *(const float4*)(zp + col);
                }
            }
            {   // stage E tile: 128 codes x 64 d
                const float* ep = E + (size_t)(k0 + ek) * DIM + d0;
                float* ed = es + ek * 68;
                #pragma unroll
                for (int q = 0; q < 8; ++q) {
                    int col = esb * 4 + q * 8;
                    *(float4*)(ed + col) = *(const float4*)(ep + col);
                }
            }
            __syncthreads();
            // compute: 16 d-quads
            for (int dg = 0; dg < 16; ++dg) {
                float4 zv[4], ev[8];
                #pragma unroll
                for (int i = 0; i < 4; ++i)
                    zv[i] = *(const float4*)(zs + (r * 4 + i) * 68 + dg * 4);
                #pragma unroll
                for (int j = 0; j < 8; ++j)
                    ev[j] = *(const float4*)(es + (c + 16 * j) * 68 + dg * 4);
                #pragma unroll
                for (int i = 0; i < 4; ++i)
                    #pragma unroll
                    for (int j = 0; j < 8; ++j)
                        acc[i][j] += zv[i].x * ev[j].x + zv[i].y * ev[j].y
                                   + zv[i].z * ev[j].z + zv[i].w * ev[j].w;
            }
        }
        // epilogue: d = fl(fl(An + ||e||^2) - 2*z.e) at magnitude ~256,
        // exactly mirroring the reference's (A + B) - C elementwise sequence.
        // (2*acc is exact in fp32; fma contraction cannot change the result.)
        #pragma unroll
        for (int i = 0; i < 4; ++i) {
            #pragma unroll
            for (int j = 0; j < 8; ++j) {
                int kk = c + 16 * j;
                float S = An[i] + sq[kk];
                float dv = S - 2.0f * acc[i][j];
                int gi = k0 + kk;
                // first-index tie-break (gi ascends per lane over time)
                if (dv < best[i] || (dv == best[i] && gi < bidx[i])) {
                    best[i] = dv; bidx[i] = gi;
                }
            }
        }
    }
    // cross-lane merge within each r-group (16 lanes of one wave)
    #pragma unroll
    for (int i = 0; i < 4; ++i) {
        float v = best[i]; int id = bidx[i];
        #pragma unroll
        for (int m = 1; m < 16; m <<= 1) {
            float ov = __shfl_xor(v, m);
            int   oi = __shfl_xor(id, m);
            if (ov < v || (ov == v && oi < id)) { v = ov; id = oi; }
        }
        if (c == 0) idx_out[tok0 + r * 4 + i] = (float)id;
    }
}

// ------- Kernel C: gather quantized, loss partial, counts, dw atomics -------
__global__ __launch_bounds__(256) void gather_kernel(
        const float* __restrict__ z, const float* __restrict__ E,
        const float* __restrict__ idx_f, float* __restrict__ quant,
        float* __restrict__ loss_acc, float* __restrict__ counts,
        float* __restrict__ dw) {
    __shared__ float ls[4];
    const int wave = threadIdx.x >> 6;
    const int lane = threadIdx.x & 63;
    const int token = blockIdx.x * 4 + wave;
    const int idx = (int)idx_f[token];

    const float4 ev = *(const float4*)(E + (size_t)idx * DIM + lane * 4);
    const float4 zv = *(const float4*)(z + (size_t)token * DIM + lane * 4);
    *(float4*)(quant + (size_t)token * DIM + lane * 4) = ev;

    float dx = zv.x - ev.x, dy = zv.y - ev.y, dz = zv.z - ev.z, dww = zv.w - ev.w;
    float l = dx * dx + dy * dy + dz * dz + dww * dww;

    float* dwp = dw + (size_t)idx * DIM + lane * 4;
    atomicAdd(dwp + 0, zv.x);
    atomicAdd(dwp + 1, zv.y);
    atomicAdd(dwp + 2, zv.z);
    atomicAdd(dwp + 3, zv.w);
    if (lane == 0) atomicAdd(counts + idx, 1.0f);

    #pragma unroll
    for (int off = 32; off > 0; off >>= 1) l += __shfl_down(l, off);
    if (lane == 0) ls[wave] = l;
    __syncthreads();
    if (threadIdx.x == 0)
        atomicAdd(loss_acc, ls[0] + ls[1] + ls[2] + ls[3]);
}

// ------- Kernel D: finalize cluster size + loss (1 block, 1024 thr) -------
__global__ __launch_bounds__(1024) void cs_kernel(
        const float* __restrict__ ema_cs, float* __restrict__ cs_inout,
        float* __restrict__ loss_inout) {
    __shared__ float red[1024];
    const int k = threadIdx.x;
    float pre = ema_cs[k] * DECAY + (1.0f - DECAY) * cs_inout[k];
    red[k] = pre;
    __syncthreads();
    for (int s = 512; s > 0; s >>= 1) {
        if (k < s) red[k] += red[k + s];
        __syncthreads();
    }
    float n = red[0];
    cs_inout[k] = (pre + EPSILON) / (n + KCODES * EPSILON) * n;
    if (k == 0)
        loss_inout[0] = COMMITMENT_COST * loss_inout[0] / (float)((size_t)NTOK * DIM);
}

// ------- Kernel E: new_ema_w & new_embedding -------
__global__ __launch_bounds__(256) void emaw_kernel(
        const float* __restrict__ ema_w, const float* __restrict__ cs,
        float* __restrict__ emaw_inout /* holds dw */, float* __restrict__ emb_out) {
    const int i = blockIdx.x * 256 + threadIdx.x;   // float4 index, 65536 total
    const int k = i >> 6;                           // 64 float4 per row
    float4 d = ((const float4*)emaw_inout)[i];
    float4 w = ((const float4*)ema_w)[i];
    float4 nw;
    nw.x = w.x * DECAY + (1.0f - DECAY) * d.x;
    nw.y = w.y * DECAY + (1.0f - DECAY) * d.y;
    nw.z = w.z * DECAY + (1.0f - DECAY) * d.z;
    nw.w = w.w * DECAY + (1.0f - DECAY) * d.w;
    ((float4*)emaw_inout)[i] = nw;
    float inv = 1.0f / cs[k];
    float4 e; e.x = nw.x * inv; e.y = nw.y * inv; e.z = nw.z * inv; e.w = nw.w * inv;
    ((float4*)emb_out)[i] = e;
}

extern "C" void kernel_launch(void* const* d_in, const int* in_sizes, int n_in,
                              void* d_out, int out_size, void* d_ws, size_t ws_size,
                              hipStream_t stream) {
    const float* z      = (const float*)d_in[0];
    const float* E      = (const float*)d_in[1];
    const float* ema_cs = (const float*)d_in[2];
    const float* ema_w  = (const float*)d_in[3];
    float* out = (float*)d_out;

    // zsq scratch at head of quantized slot; gather overwrites it afterwards
    float* zsq = out + O_QUANT;

    // zero accumulators: [O_LOSS, O_EMAW + 262144) covers loss/idx/counts/dw
    hipMemsetAsync(out + O_LOSS, 0, (size_t)(1 + 32768 + 1024 + 262144) * 4, stream);

    zsq_kernel<<<NTOK / 4, 256, 0, stream>>>(z, zsq);
    esq_kernel<<<256, 256, 0, stream>>>(E, out + O_EMB);
    dist_argmin_kernel<<<NTOK / 64, 256, 0, stream>>>(z, E, out + O_EMB, zsq,
                                                      out + O_IDX);
    gather_kernel<<<NTOK / 4, 256, 0, stream>>>(z, E, out + O_IDX, out + O_QUANT,
                                                out + O_LOSS, out + O_CS, out + O_EMAW);
    cs_kernel<<<1, 1024, 0, stream>>>(ema_cs, out + O_CS, out + O_LOSS);
    emaw_kernel<<<262144 / 1024, 256, 0, stream>>>(ema_w, out + O_CS, out + O_EMAW,
                                                   out + O_EMB);
}

// Round 4
// 545.191 us; speedup vs baseline: 1.0409x; 1.0409x over previous
//
#include <hip/hip_runtime.h>
#include <math.h>

#define COMMITMENT_COST 0.25f
#define DECAY 0.99f
#define EPSILON 1e-05f
#define KCODES 1024
#define DIM 256
#define NTOK 32768

// out-buffer float offsets (concatenated return tuple)
#define O_QUANT 0
#define O_LOSS  8388608
#define O_IDX   8388609
#define O_CS    8421377
#define O_EMAW  8422401
#define O_EMB   8684545

// scratch inside the quantized slot (overwritten by quantloss at the end):
// [0,32768)       zsq
// [32768,65536)   bucket
// [65536,66560)   cnt (int)
// [66560,67585)   off (int, 1025)
// [67585,68609)   cursor (int)
#define S_ZSQ    0
#define S_BUCKET 32768
#define S_CNT    65536
#define S_OFF    66560
#define S_CURSOR 67585

// ---------------- zsq[n] = sum_d z[n][d]^2 ----------------
__global__ void zsq_kernel(const float* __restrict__ z, float* __restrict__ zsq) {
    int wave = threadIdx.x >> 6;
    int lane = threadIdx.x & 63;
    int token = blockIdx.x * 4 + wave;
    const float4* zp = (const float4*)(z + (size_t)token * DIM);
    float4 v = zp[lane];
    float s = v.x * v.x + v.y * v.y + v.z * v.z + v.w * v.w;
    #pragma unroll
    for (int off = 32; off > 0; off >>= 1) s += __shfl_down(s, off);
    if (lane == 0) zsq[token] = s;
}

// ---------------- esq[k] = sum_d E[k][d]^2 ----------------
__global__ void esq_kernel(const float* __restrict__ E, float* __restrict__ esq) {
    int wave = threadIdx.x >> 6;
    int lane = threadIdx.x & 63;
    int k = blockIdx.x * 4 + wave;
    const float4* ep = (const float4*)(E + (size_t)k * DIM);
    float4 v = ep[lane];
    float s = v.x * v.x + v.y * v.y + v.z * v.z + v.w * v.w;
    #pragma unroll
    for (int off = 32; off > 0; off >>= 1) s += __shfl_down(s, off);
    if (lane == 0) esq[k] = s;
}

// ---------------- fused distances + argmin ----------------
// d = fl(fl(||z||^2 + ||e||^2) - 2*z.e) at magnitude ~256, first-index ties.
// block 256 thr; tile 64 tok x 256 codes; K-tiles of 256; 32-d chunks;
// thread tile 8 tok x 8 codes (codes c + 32j). LDS 46 KB.
__global__ __launch_bounds__(256) void dist_argmin_kernel(
        const float* __restrict__ z, const float* __restrict__ E,
        const float* __restrict__ esq, const float* __restrict__ zsq,
        float* __restrict__ idx_out) {
    __shared__ float zs[64 * 36];
    __shared__ float es[256 * 36];

    const int tid = threadIdx.x;
    const int r = tid >> 5;          // 0..7 -> tokens r*8 .. r*8+7
    const int c = tid & 31;          // codes c + 32*j, j=0..7
    const int tok0 = blockIdx.x * 64;

    float An[8];
    #pragma unroll
    for (int i = 0; i < 8; ++i) An[i] = zsq[tok0 + r * 8 + i];

    float best[8];
    int bidx[8];
    #pragma unroll
    for (int i = 0; i < 8; ++i) { best[i] = 3.4e38f; bidx[i] = 0x7fffffff; }

    for (int kt = 0; kt < 4; ++kt) {
        const int k0 = kt * 256;
        float sq[8];
        #pragma unroll
        for (int j = 0; j < 8; ++j) sq[j] = esq[k0 + c + 32 * j];

        float acc[8][8];
        #pragma unroll
        for (int i = 0; i < 8; ++i)
            #pragma unroll
            for (int j = 0; j < 8; ++j) acc[i][j] = 0.0f;

        for (int dc = 0; dc < 8; ++dc) {
            const int d0 = dc * 32;
            __syncthreads();
            // stage z tile: 64 tok x 32 d (512 f4, 2/thread, coalesced)
            #pragma unroll
            for (int q = 0; q < 2; ++q) {
                int g = tid + 256 * q;
                int row = g >> 3, col = (g & 7) * 4;
                *(float4*)(zs + row * 36 + col) =
                    *(const float4*)(z + (size_t)(tok0 + row) * DIM + d0 + col);
            }
            // stage E tile: 256 codes x 32 d (2048 f4, 8/thread, coalesced)
            #pragma unroll
            for (int q = 0; q < 8; ++q) {
                int g = tid + 256 * q;
                int row = g >> 3, col = (g & 7) * 4;
                *(float4*)(es + row * 36 + col) =
                    *(const float4*)(E + (size_t)(k0 + row) * DIM + d0 + col);
            }
            __syncthreads();
            #pragma unroll
            for (int dg = 0; dg < 8; ++dg) {
                float4 zv[8];
                #pragma unroll
                for (int i = 0; i < 8; ++i)
                    zv[i] = *(const float4*)(zs + (r * 8 + i) * 36 + dg * 4);
                #pragma unroll
                for (int j = 0; j < 8; ++j) {
                    float4 ev = *(const float4*)(es + (c + 32 * j) * 36 + dg * 4);
                    #pragma unroll
                    for (int i = 0; i < 8; ++i) {
                        acc[i][j] = fmaf(zv[i].x, ev.x, acc[i][j]);
                        acc[i][j] = fmaf(zv[i].y, ev.y, acc[i][j]);
                        acc[i][j] = fmaf(zv[i].z, ev.z, acc[i][j]);
                        acc[i][j] = fmaf(zv[i].w, ev.w, acc[i][j]);
                    }
                }
            }
        }
        // epilogue: mirror reference rounding sequence
        #pragma unroll
        for (int i = 0; i < 8; ++i)
            #pragma unroll
            for (int j = 0; j < 8; ++j) {
                float S = An[i] + sq[j];
                float dv = S - 2.0f * acc[i][j];
                int gi = k0 + c + 32 * j;
                if (dv < best[i] || (dv == best[i] && gi < bidx[i])) {
                    best[i] = dv; bidx[i] = gi;
                }
            }
    }
    // cross-lane merge over the 32 c-lanes of each r-group
    #pragma unroll
    for (int i = 0; i < 8; ++i) {
        float v = best[i]; int id = bidx[i];
        #pragma unroll
        for (int m = 1; m < 32; m <<= 1) {
            float ov = __shfl_xor(v, m);
            int   oi = __shfl_xor(id, m);
            if (ov < v || (ov == v && oi < id)) { v = ov; id = oi; }
        }
        if (c == 0) idx_out[tok0 + r * 8 + i] = (float)id;
    }
}

// ---------------- CSR phase 1: per-block LDS histogram ----------------
__global__ __launch_bounds__(256) void hist_kernel(
        const float* __restrict__ idx_f, int* __restrict__ cnt) {
    __shared__ int h[KCODES];
    #pragma unroll
    for (int q = 0; q < 4; ++q) h[threadIdx.x + 256 * q] = 0;
    __syncthreads();
    int t = blockIdx.x * 256 + threadIdx.x;
    atomicAdd(&h[(int)idx_f[t]], 1);
    __syncthreads();
    #pragma unroll
    for (int q = 0; q < 4; ++q) {
        int k = threadIdx.x + 256 * q;
        if (h[k]) atomicAdd(&cnt[k], h[k]);
    }
}

// ---------------- CSR phase 2: prefix scan (1 block) ----------------
__global__ __launch_bounds__(1024) void scan_kernel(
        const int* __restrict__ cnt, int* __restrict__ off,
        int* __restrict__ cursor, float* __restrict__ counts_f) {
    __shared__ int s[KCODES];
    const int k = threadIdx.x;
    int v = cnt[k];
    counts_f[k] = (float)v;
    s[k] = v;
    __syncthreads();
    for (int d = 1; d < KCODES; d <<= 1) {
        int add = (k >= d) ? s[k - d] : 0;
        __syncthreads();
        s[k] += add;
        __syncthreads();
    }
    int excl = s[k] - v;
    off[k] = excl;
    cursor[k] = excl;
    if (k == KCODES - 1) off[KCODES] = s[k];
}

// ---------------- CSR phase 3: scatter tokens into buckets ----------------
__global__ __launch_bounds__(256) void scatter_kernel(
        const float* __restrict__ idx_f, int* __restrict__ cursor,
        int* __restrict__ bucket) {
    int t = blockIdx.x * 256 + threadIdx.x;
    int k = (int)idx_f[t];
    int p = atomicAdd(&cursor[k], 1);
    bucket[p] = t;
}

// ---------------- CSR phase 4: dw[k] = sum of z rows, no atomics ----------
__global__ __launch_bounds__(256) void dwsum_kernel(
        const float* __restrict__ z, const int* __restrict__ off,
        const int* __restrict__ bucket, float* __restrict__ dw) {
    const int k = blockIdx.x;
    const int s = off[k], e = off[k + 1];
    float acc = 0.0f;
    for (int t = s; t < e; ++t) {
        int token = bucket[t];
        acc += z[(size_t)token * DIM + threadIdx.x];
    }
    dw[(size_t)k * DIM + threadIdx.x] = acc;
}

// ---------------- quantized gather + loss ----------------
__global__ __launch_bounds__(256) void quantloss_kernel(
        const float* __restrict__ z, const float* __restrict__ E,
        const float* __restrict__ idx_f, float* __restrict__ quant,
        float* __restrict__ loss_acc) {
    __shared__ float ls[4];
    const int wave = threadIdx.x >> 6;
    const int lane = threadIdx.x & 63;
    const int token = blockIdx.x * 4 + wave;
    const int idx = (int)idx_f[token];

    const float4 ev = *(const float4*)(E + (size_t)idx * DIM + lane * 4);
    const float4 zv = *(const float4*)(z + (size_t)token * DIM + lane * 4);
    *(float4*)(quant + (size_t)token * DIM + lane * 4) = ev;

    float dx = zv.x - ev.x, dy = zv.y - ev.y, dz = zv.z - ev.z, dww = zv.w - ev.w;
    float l = dx * dx + dy * dy + dz * dz + dww * dww;
    #pragma unroll
    for (int off = 32; off > 0; off >>= 1) l += __shfl_down(l, off);
    if (lane == 0) ls[wave] = l;
    __syncthreads();
    if (threadIdx.x == 0)
        atomicAdd(loss_acc, ls[0] + ls[1] + ls[2] + ls[3]);
}

// ---------------- finalize cluster size + loss ----------------
__global__ __launch_bounds__(1024) void cs_kernel(
        const float* __restrict__ ema_cs, float* __restrict__ cs_inout,
        float* __restrict__ loss_inout) {
    __shared__ float red[KCODES];
    const int k = threadIdx.x;
    float pre = ema_cs[k] * DECAY + (1.0f - DECAY) * cs_inout[k];
    red[k] = pre;
    __syncthreads();
    for (int s = 512; s > 0; s >>= 1) {
        if (k < s) red[k] += red[k + s];
        __syncthreads();
    }
    float n = red[0];
    cs_inout[k] = (pre + EPSILON) / (n + KCODES * EPSILON) * n;
    if (k == 0)
        loss_inout[0] = COMMITMENT_COST * loss_inout[0] / (float)((size_t)NTOK * DIM);
}

// ---------------- new_ema_w & new_embedding ----------------
__global__ __launch_bounds__(256) void emaw_kernel(
        const float* __restrict__ ema_w, const float* __restrict__ cs,
        float* __restrict__ emaw_inout /* holds dw */, float* __restrict__ emb_out) {
    const int i = blockIdx.x * 256 + threadIdx.x;
    const int k = i >> 6;
    float4 d = ((const float4*)emaw_inout)[i];
    float4 w = ((const float4*)ema_w)[i];
    float4 nw;
    nw.x = w.x * DECAY + (1.0f - DECAY) * d.x;
    nw.y = w.y * DECAY + (1.0f - DECAY) * d.y;
    nw.z = w.z * DECAY + (1.0f - DECAY) * d.z;
    nw.w = w.w * DECAY + (1.0f - DECAY) * d.w;
    ((float4*)emaw_inout)[i] = nw;
    float inv = 1.0f / cs[k];
    float4 e; e.x = nw.x * inv; e.y = nw.y * inv; e.z = nw.z * inv; e.w = nw.w * inv;
    ((float4*)emb_out)[i] = e;
}

extern "C" void kernel_launch(void* const* d_in, const int* in_sizes, int n_in,
                              void* d_out, int out_size, void* d_ws, size_t ws_size,
                              hipStream_t stream) {
    const float* z      = (const float*)d_in[0];
    const float* E      = (const float*)d_in[1];
    const float* ema_cs = (const float*)d_in[2];
    const float* ema_w  = (const float*)d_in[3];
    float* out = (float*)d_out;

    float* zsq    = out + S_ZSQ;
    int*   bucket = (int*)(out + S_BUCKET);
    int*   cnt    = (int*)(out + S_CNT);
    int*   off    = (int*)(out + S_OFF);
    int*   cursor = (int*)(out + S_CURSOR);

    hipMemsetAsync(out + O_LOSS, 0, 4, stream);              // loss accumulator
    hipMemsetAsync(cnt, 0, KCODES * 4, stream);              // histogram

    zsq_kernel<<<NTOK / 4, 256, 0, stream>>>(z, zsq);
    esq_kernel<<<KCODES / 4, 256, 0, stream>>>(E, out + O_EMB);
    dist_argmin_kernel<<<NTOK / 64, 256, 0, stream>>>(z, E, out + O_EMB, zsq,
                                                      out + O_IDX);
    hist_kernel<<<NTOK / 256, 256, 0, stream>>>(out + O_IDX, cnt);
    scan_kernel<<<1, 1024, 0, stream>>>(cnt, off, cursor, out + O_CS);
    scatter_kernel<<<NTOK / 256, 256, 0, stream>>>(out + O_IDX, cursor, bucket);
    dwsum_kernel<<<KCODES, 256, 0, stream>>>(z, off, bucket, out + O_EMAW);
    quantloss_kernel<<<NTOK / 4, 256, 0, stream>>>(z, E, out + O_IDX,
                                                   out + O_QUANT, out + O_LOSS);
    cs_kernel<<<1, 1024, 0, stream>>>(ema_cs, out + O_CS, out + O_LOSS);
    emaw_kernel<<<(KCODES * DIM / 4) / 256, 256, 0, stream>>>(ema_w, out + O_CS,
                                                              out + O_EMAW,
                                                              out + O_EMB);
}